// Round 1
// baseline (176.881 us; speedup 1.0000x reference)
//
#include <hip/hip_runtime.h>
#include <math.h>

#define NRAYS 8192
#define NS 512
#define HID 32

// One wave (64 lanes) per ray. Lane i handles samples t = 64k + i.
// Weights packed in LDS as [j][8] = {W1[0][j],W1[1][j],W1[2][j],b1[j],Wc[j][0..2],Wd[j]},
// extras at [256..259] = {bc0,bc1,bc2,bd0}. All weight reads are uniform-address
// broadcasts (no bank conflicts).
__global__ __launch_bounds__(256) void render_kernel(
    const float* __restrict__ o_, const float* __restrict__ d_,
    const float* __restrict__ aabb, const float* __restrict__ u_,
    const float* __restrict__ W1, const float* __restrict__ b1,
    const float* __restrict__ Wc, const float* __restrict__ bc,
    const float* __restrict__ Wd, const float* __restrict__ bd,
    float* __restrict__ out)
{
    __shared__ float wsh[272];
    const int tid = threadIdx.x;

    // Per-block weight repack into LDS (weight region is L2-hot after first blocks).
    if (tid < HID) {
        const int j = tid;
        wsh[j * 8 + 0] = W1[0 * HID + j];
        wsh[j * 8 + 1] = W1[1 * HID + j];
        wsh[j * 8 + 2] = W1[2 * HID + j];
        wsh[j * 8 + 3] = b1[j];
        wsh[j * 8 + 4] = Wc[j * 3 + 0];
        wsh[j * 8 + 5] = Wc[j * 3 + 1];
        wsh[j * 8 + 6] = Wc[j * 3 + 2];
        wsh[j * 8 + 7] = Wd[j];
    } else if (tid == HID) {
        wsh[256] = bc[0]; wsh[257] = bc[1]; wsh[258] = bc[2]; wsh[259] = bd[0];
    }
    __syncthreads();

    const int lane = tid & 63;
    const int ray  = (blockIdx.x << 2) + (tid >> 6);
    if (ray >= NRAYS) return;

    const float ox = o_[ray * 3 + 0], oy = o_[ray * 3 + 1], oz = o_[ray * 3 + 2];
    const float dx = d_[ray * 3 + 0], dy = d_[ray * 3 + 1], dz = d_[ray * 3 + 2];
    const float lox = aabb[0], loy = aabb[1], loz = aabb[2];
    const float hix = aabb[3], hiy = aabb[4], hiz = aabb[5];

    // Slab test (plain IEEE division; +-inf handled like the reference).
    float t1 = (lox - ox) / dx, t2 = (hix - ox) / dx;
    float tnear = fminf(t1, t2), tfar = fmaxf(t1, t2);
    t1 = (loy - oy) / dy; t2 = (hiy - oy) / dy;
    tnear = fmaxf(tnear, fminf(t1, t2)); tfar = fminf(tfar, fmaxf(t1, t2));
    t1 = (loz - oz) / dz; t2 = (hiz - oz) / dz;
    tnear = fmaxf(tnear, fminf(t1, t2)); tfar = fminf(tfar, fmaxf(t1, t2));
    tnear = fmaxf(tnear, 0.0f);

    float4 res = make_float4(0.0f, 0.0f, 0.0f, 0.0f);

    if (tnear < tfar) {  // active ray (wave-uniform branch)
        const float dnorm = sqrtf(dx * dx + dy * dy + dz * dz);
        const float dt = (tfar - tnear) * (1.0f / (float)NS);
        const float sx = 2.0f / (hix - lox);
        const float sy = 2.0f / (hiy - loy);
        const float sz = 2.0f / (hiz - loz);
        const float* __restrict__ urow = u_ + (size_t)ray * NS;

        const float bc0 = wsh[256], bc1 = wsh[257], bc2 = wsh[258], bd0 = wsh[259];

        float accR = 0.0f, accG = 0.0f, accB = 0.0f, accA = 0.0f;
        float carry = 0.0f;

        for (int k = 0; k < NS / 64; ++k) {
            const int t = (k << 6) + lane;
            const float ut = urow[t];
            const float un = (t < NS - 1) ? urow[t + 1] : 0.0f;
            const float ts = fmaf(dt, (float)t + ut, tnear);
            float delta = (t < NS - 1) ? dt * (1.0f + un - ut)
                                       : (tfar + 1.0f) - ts;   // BOOSTER = 1.0
            delta *= dnorm;

            // xyz -> ndc (sx==1 exactly for this aabb, matching ref bitwise)
            const float px = fmaf(dx, ts, ox);
            const float py = fmaf(dy, ts, oy);
            const float pz = fmaf(dz, ts, oz);
            const float nx = (px - lox) * sx - 1.0f;
            const float ny = (py - loy) * sy - 1.0f;
            const float nz = (pz - loz) * sz - 1.0f;
            const bool inbox = (fabsf(nx) <= 1.0f) && (fabsf(ny) <= 1.0f) && (fabsf(nz) <= 1.0f);

            // MLP: h = relu(ndc @ W1 + b1); color_pre = h@Wc+bc; dens_pre = h@Wd+bd
            float cr = bc0, cg = bc1, cb = bc2, dd = bd0;
            #pragma unroll
            for (int j = 0; j < HID; ++j) {
                const float4 wa = reinterpret_cast<const float4*>(wsh)[2 * j];
                const float4 wb = reinterpret_cast<const float4*>(wsh)[2 * j + 1];
                float h = fmaf(nx, wa.x, fmaf(ny, wa.y, fmaf(nz, wa.z, wa.w)));
                h = fmaxf(h, 0.0f);
                cr = fmaf(h, wb.x, cr);
                cg = fmaf(h, wb.y, cg);
                cb = fmaf(h, wb.z, cb);
                dd = fmaf(h, wb.w, dd);
            }

            // softplus (stable, matches jax.nn.softplus) + bounds mask
            float dens = fmaxf(dd, 0.0f) + __logf(1.0f + __expf(-fabsf(dd)));
            dens = inbox ? dens : 0.0f;

            const float sd = dens * delta;

            // 64-lane inclusive Kogge-Stone scan of sd
            float cum = sd;
            #pragma unroll
            for (int off = 1; off < 64; off <<= 1) {
                const float v = __shfl_up(cum, off);
                cum += (lane >= off) ? v : 0.0f;
            }
            const float Ci = carry + cum;       // inclusive cumsum incl. previous batches
            const float Ce = Ci - sd;           // exclusive
            const float w = __expf(-Ce) - __expf(-Ci);  // trans*(1-exp(-sd))

            const float colR = __builtin_amdgcn_rcpf(1.0f + __expf(-cr));
            const float colG = __builtin_amdgcn_rcpf(1.0f + __expf(-cg));
            const float colB = __builtin_amdgcn_rcpf(1.0f + __expf(-cb));

            accR = fmaf(w, colR, accR);
            accG = fmaf(w, colG, accG);
            accB = fmaf(w, colB, accB);
            accA += w;

            carry += __shfl(cum, 63);
            if (carry > 30.0f) break;  // trans < e^-30: remaining weights negligible (uniform)
        }

        // 64-lane butterfly sum of the four accumulators
        #pragma unroll
        for (int off = 32; off; off >>= 1) {
            accR += __shfl_xor(accR, off);
            accG += __shfl_xor(accG, off);
            accB += __shfl_xor(accB, off);
            accA += __shfl_xor(accA, off);
        }
        res = make_float4(accR, accG, accB, accA);
    }

    if (lane == 0) {
        reinterpret_cast<float4*>(out)[ray] = res;
    }
}

extern "C" void kernel_launch(void* const* d_in, const int* in_sizes, int n_in,
                              void* d_out, int out_size, void* d_ws, size_t ws_size,
                              hipStream_t stream) {
    const float* o_   = (const float*)d_in[0];
    const float* d_   = (const float*)d_in[1];
    const float* aabb = (const float*)d_in[2];
    const float* u_   = (const float*)d_in[3];
    const float* W1   = (const float*)d_in[4];
    const float* b1   = (const float*)d_in[5];
    const float* Wc   = (const float*)d_in[6];
    const float* bc   = (const float*)d_in[7];
    const float* Wd   = (const float*)d_in[8];
    const float* bd   = (const float*)d_in[9];
    float* out = (float*)d_out;

    // 4 waves/block, one wave per ray -> 8192/4 = 2048 blocks (32 waves/CU resident)
    render_kernel<<<NRAYS / 4, 256, 0, stream>>>(o_, d_, aabb, u_, W1, b1, Wc, bc, Wd, bd, out);
}

// Round 3
// 128.138 us; speedup vs baseline: 1.3804x; 1.3804x over previous
//
#include <hip/hip_runtime.h>
#include <math.h>

#define NRAYS 8192
#define NS 512
#define HID 32

typedef float f32x2 __attribute__((ext_vector_type(2)));

// One wave (64 lanes) per ray. Lane i handles samples t = 64k + i.
// Weights packed in LDS pair-interleaved over hidden units (j,j+1) so the MLP
// runs on v_pk_fma_f32 / v_pk_max_f32 (2 FMA per instruction):
// per j-pair p (16 floats = 4 x b128):
//   [0..1]=W1[0][2p,2p+1] [2..3]=W1[1][..] [4..5]=W1[2][..] [6..7]=b1[..]
//   [8..9]=Wc[..][0] [10..11]=Wc[..][1] [12..13]=Wc[..][2] [14..15]=Wd[..]
// extras at [256..259] = {bc0,bc1,bc2,bd0}. All weight reads are uniform-address
// LDS broadcasts (no bank conflicts).
__global__ __launch_bounds__(256) void render_kernel(
    const float* __restrict__ o_, const float* __restrict__ d_,
    const float* __restrict__ aabb, const float* __restrict__ u_,
    const float* __restrict__ W1, const float* __restrict__ b1,
    const float* __restrict__ Wc, const float* __restrict__ bc,
    const float* __restrict__ Wd, const float* __restrict__ bd,
    float* __restrict__ out)
{
    __shared__ float wsh[272];
    const int tid = threadIdx.x;

    if (tid < HID) {
        const int j = tid, p = j >> 1, h = j & 1;
        float* base = wsh + p * 16;
        base[0 + h]  = W1[0 * HID + j];
        base[2 + h]  = W1[1 * HID + j];
        base[4 + h]  = W1[2 * HID + j];
        base[6 + h]  = b1[j];
        base[8 + h]  = Wc[j * 3 + 0];
        base[10 + h] = Wc[j * 3 + 1];
        base[12 + h] = Wc[j * 3 + 2];
        base[14 + h] = Wd[j];
    } else if (tid == HID) {
        wsh[256] = bc[0]; wsh[257] = bc[1]; wsh[258] = bc[2]; wsh[259] = bd[0];
    }
    __syncthreads();

    const int lane = tid & 63;
    const int ray  = (blockIdx.x << 2) + (tid >> 6);
    if (ray >= NRAYS) return;

    const float ox = o_[ray * 3 + 0], oy = o_[ray * 3 + 1], oz = o_[ray * 3 + 2];
    const float dx = d_[ray * 3 + 0], dy = d_[ray * 3 + 1], dz = d_[ray * 3 + 2];
    const float lox = aabb[0], loy = aabb[1], loz = aabb[2];
    const float hix = aabb[3], hiy = aabb[4], hiz = aabb[5];

    // Slab test (plain IEEE division; +-inf handled like the reference).
    float t1 = (lox - ox) / dx, t2 = (hix - ox) / dx;
    float tnear = fminf(t1, t2), tfar = fmaxf(t1, t2);
    t1 = (loy - oy) / dy; t2 = (hiy - oy) / dy;
    tnear = fmaxf(tnear, fminf(t1, t2)); tfar = fminf(tfar, fmaxf(t1, t2));
    t1 = (loz - oz) / dz; t2 = (hiz - oz) / dz;
    tnear = fmaxf(tnear, fminf(t1, t2)); tfar = fminf(tfar, fmaxf(t1, t2));
    tnear = fmaxf(tnear, 0.0f);

    float4 res = make_float4(0.0f, 0.0f, 0.0f, 0.0f);

    if (tnear < tfar) {  // active ray (wave-uniform branch)
        const float dnorm = sqrtf(dx * dx + dy * dy + dz * dz);
        const float dt = (tfar - tnear) * (1.0f / (float)NS);
        const float sx = 2.0f / (hix - lox);
        const float sy = 2.0f / (hiy - loy);
        const float sz = 2.0f / (hiz - loz);
        const float* __restrict__ urow = u_ + (size_t)ray * NS;

        const float bc0 = wsh[256], bc1 = wsh[257], bc2 = wsh[258], bd0 = wsh[259];

        float accR = 0.0f, accG = 0.0f, accB = 0.0f, accA = 0.0f;
        float carry = 0.0f;

        for (int k = 0; k < NS / 64; ++k) {
            const int t = (k << 6) + lane;
            const float ut = urow[t];
            const float un = (t < NS - 1) ? urow[t + 1] : 0.0f;
            const float ts = fmaf(dt, (float)t + ut, tnear);
            float delta = (t < NS - 1) ? dt * (1.0f + un - ut)
                                       : (tfar + 1.0f) - ts;   // BOOSTER = 1.0
            delta *= dnorm;

            const float px = fmaf(dx, ts, ox);
            const float py = fmaf(dy, ts, oy);
            const float pz = fmaf(dz, ts, oz);
            const float nx = (px - lox) * sx - 1.0f;
            const float ny = (py - loy) * sy - 1.0f;
            const float nz = (pz - loz) * sz - 1.0f;
            const bool inbox = (fabsf(nx) <= 1.0f) && (fabsf(ny) <= 1.0f) && (fabsf(nz) <= 1.0f);

            // Packed MLP over hidden-unit pairs: 8 pk ops per 2 hidden units.
            const f32x2 nx2 = {nx, nx};
            const f32x2 ny2 = {ny, ny};
            const f32x2 nz2 = {nz, nz};
            f32x2 cr2 = {bc0, 0.0f};
            f32x2 cg2 = {bc1, 0.0f};
            f32x2 cb2 = {bc2, 0.0f};
            f32x2 dd2 = {bd0, 0.0f};
            const float4* __restrict__ wq = reinterpret_cast<const float4*>(wsh);
            #pragma unroll 8
            for (int p = 0; p < HID / 2; ++p) {
                const float4 q0 = wq[p * 4 + 0];   // W1x pair, W1y pair
                const float4 q1 = wq[p * 4 + 1];   // W1z pair, b1 pair
                const float4 q2 = wq[p * 4 + 2];   // WcR pair, WcG pair
                const float4 q3 = wq[p * 4 + 3];   // WcB pair, Wd pair
                const f32x2 w1x = {q0.x, q0.y}, w1y = {q0.z, q0.w};
                const f32x2 w1z = {q1.x, q1.y}, b12 = {q1.z, q1.w};
                const f32x2 wcr = {q2.x, q2.y}, wcg = {q2.z, q2.w};
                const f32x2 wcb = {q3.x, q3.y}, wd2 = {q3.z, q3.w};
                f32x2 h2 = __builtin_elementwise_fma(nx2, w1x,
                           __builtin_elementwise_fma(ny2, w1y,
                           __builtin_elementwise_fma(nz2, w1z, b12)));
                h2 = __builtin_elementwise_max(h2, (f32x2){0.0f, 0.0f});
                cr2 = __builtin_elementwise_fma(h2, wcr, cr2);
                cg2 = __builtin_elementwise_fma(h2, wcg, cg2);
                cb2 = __builtin_elementwise_fma(h2, wcb, cb2);
                dd2 = __builtin_elementwise_fma(h2, wd2, dd2);
            }
            const float cr = cr2.x + cr2.y;
            const float cg = cg2.x + cg2.y;
            const float cb = cb2.x + cb2.y;
            const float dd = dd2.x + dd2.y;

            // softplus (stable, matches jax.nn.softplus) + bounds mask
            float dens = fmaxf(dd, 0.0f) + __logf(1.0f + __expf(-fabsf(dd)));
            dens = inbox ? dens : 0.0f;

            const float sd = dens * delta;

            // 64-lane inclusive Kogge-Stone scan of sd
            float cum = sd;
            #pragma unroll
            for (int off = 1; off < 64; off <<= 1) {
                const float v = __shfl_up(cum, off);
                cum += (lane >= off) ? v : 0.0f;
            }
            const float Ci = carry + cum;       // inclusive cumsum incl. previous batches
            const float Ce = Ci - sd;           // exclusive
            const float w = __expf(-Ce) - __expf(-Ci);  // trans*(1-exp(-sd))

            const float colR = __builtin_amdgcn_rcpf(1.0f + __expf(-cr));
            const float colG = __builtin_amdgcn_rcpf(1.0f + __expf(-cg));
            const float colB = __builtin_amdgcn_rcpf(1.0f + __expf(-cb));

            accR = fmaf(w, colR, accR);
            accG = fmaf(w, colG, accG);
            accB = fmaf(w, colB, accB);
            accA += w;

            carry += __shfl(cum, 63);
            if (carry > 30.0f) break;  // trans < e^-30: remaining weights negligible (uniform)
        }

        // 64-lane butterfly sum of the four accumulators
        #pragma unroll
        for (int off = 32; off; off >>= 1) {
            accR += __shfl_xor(accR, off);
            accG += __shfl_xor(accG, off);
            accB += __shfl_xor(accB, off);
            accA += __shfl_xor(accA, off);
        }
        res = make_float4(accR, accG, accB, accA);
    }

    if (lane == 0) {
        reinterpret_cast<float4*>(out)[ray] = res;
    }
}

extern "C" void kernel_launch(void* const* d_in, const int* in_sizes, int n_in,
                              void* d_out, int out_size, void* d_ws, size_t ws_size,
                              hipStream_t stream) {
    const float* o_   = (const float*)d_in[0];
    const float* d_   = (const float*)d_in[1];
    const float* aabb = (const float*)d_in[2];
    const float* u_   = (const float*)d_in[3];
    const float* W1   = (const float*)d_in[4];
    const float* b1   = (const float*)d_in[5];
    const float* Wc   = (const float*)d_in[6];
    const float* bc   = (const float*)d_in[7];
    const float* Wd   = (const float*)d_in[8];
    const float* bd   = (const float*)d_in[9];
    float* out = (float*)d_out;

    render_kernel<<<NRAYS / 4, 256, 0, stream>>>(o_, d_, aabb, u_, W1, b1, Wc, bc, Wd, bd, out);
}

// Round 5
// 115.846 us; speedup vs baseline: 1.5269x; 1.1061x over previous
//
#include <hip/hip_runtime.h>
#include <math.h>

#define NRAYS 8192
#define NS 512
#define HID 32
#define SPL 8   // samples per lane; 64 lanes * 8 = 512 = NS (one pass per ray)

typedef float f32x2 __attribute__((ext_vector_type(2)));

// One wave (64 lanes) per ray; lane i owns samples t = 8i..8i+7 (whole ray in
// ONE pass). MLP packed over hidden-unit pairs (v_pk_fma_f32); each weight
// quad is read from LDS once per ray and applied to all 8 samples (8-way ILP).
// Weight LDS layout per pair p (16 floats = 4 x b128):
//   [0..1]=W1[0][2p,2p+1] [2..3]=W1[1][..] [4..5]=W1[2][..] [6..7]=b1[..]
//   [8..9]=Wc[..][0] [10..11]=Wc[..][1] [12..13]=Wc[..][2] [14..15]=Wd[..]
// extras at [256..259] = {bc0,bc1,bc2,bd0}. All weight reads are uniform-address
// LDS broadcasts.
__global__ __launch_bounds__(256) void render_kernel(
    const float* __restrict__ o_, const float* __restrict__ d_,
    const float* __restrict__ aabb, const float* __restrict__ u_,
    const float* __restrict__ W1, const float* __restrict__ b1,
    const float* __restrict__ Wc, const float* __restrict__ bc,
    const float* __restrict__ Wd, const float* __restrict__ bd,
    float* __restrict__ out)
{
    __shared__ float wsh[272];
    const int tid = threadIdx.x;

    if (tid < HID) {
        const int j = tid, p = j >> 1, h = j & 1;
        float* base = wsh + p * 16;
        base[0 + h]  = W1[0 * HID + j];
        base[2 + h]  = W1[1 * HID + j];
        base[4 + h]  = W1[2 * HID + j];
        base[6 + h]  = b1[j];
        base[8 + h]  = Wc[j * 3 + 0];
        base[10 + h] = Wc[j * 3 + 1];
        base[12 + h] = Wc[j * 3 + 2];
        base[14 + h] = Wd[j];
    } else if (tid == HID) {
        wsh[256] = bc[0]; wsh[257] = bc[1]; wsh[258] = bc[2]; wsh[259] = bd[0];
    }
    __syncthreads();

    const int lane = tid & 63;
    const int ray  = (blockIdx.x << 2) + (tid >> 6);
    if (ray >= NRAYS) return;

    const float ox = o_[ray * 3 + 0], oy = o_[ray * 3 + 1], oz = o_[ray * 3 + 2];
    const float dx = d_[ray * 3 + 0], dy = d_[ray * 3 + 1], dz = d_[ray * 3 + 2];
    const float lox = aabb[0], loy = aabb[1], loz = aabb[2];
    const float hix = aabb[3], hiy = aabb[4], hiz = aabb[5];

    // Slab test (plain IEEE division; +-inf handled like the reference).
    float t1 = (lox - ox) / dx, t2 = (hix - ox) / dx;
    float tnear = fminf(t1, t2), tfar = fmaxf(t1, t2);
    t1 = (loy - oy) / dy; t2 = (hiy - oy) / dy;
    tnear = fmaxf(tnear, fminf(t1, t2)); tfar = fminf(tfar, fmaxf(t1, t2));
    t1 = (loz - oz) / dz; t2 = (hiz - oz) / dz;
    tnear = fmaxf(tnear, fminf(t1, t2)); tfar = fminf(tfar, fmaxf(t1, t2));
    tnear = fmaxf(tnear, 0.0f);

    float4 res = make_float4(0.0f, 0.0f, 0.0f, 0.0f);

    if (tnear < tfar) {  // active ray (wave-uniform branch)
        const float dnorm = sqrtf(dx * dx + dy * dy + dz * dz);
        const float dt = (tfar - tnear) * (1.0f / (float)NS);
        const float sx = 2.0f / (hix - lox);
        const float sy = 2.0f / (hiy - loy);
        const float sz = 2.0f / (hiz - loz);
        const float bc0 = wsh[256], bc1 = wsh[257], bc2 = wsh[258], bd0 = wsh[259];

        // ---- prologue: jitter, positions, deltas for this lane's 8 samples ----
        const int base_t = lane * SPL;
        const float* __restrict__ urow = u_ + (size_t)ray * NS + base_t;
        const float4 uaq = *reinterpret_cast<const float4*>(urow);
        const float4 ubq = *reinterpret_cast<const float4*>(urow + 4);
        float us[9];
        us[0] = uaq.x; us[1] = uaq.y; us[2] = uaq.z; us[3] = uaq.w;
        us[4] = ubq.x; us[5] = ubq.y; us[6] = ubq.z; us[7] = ubq.w;
        us[8] = __shfl_down(uaq.x, 1);   // u[8(i+1)]; lane 63 unused (tfar branch)

        f32x2 nx2[SPL], ny2[SPL], nz2[SPL];
        float delta[SPL];
        #pragma unroll
        for (int s = 0; s < SPL; ++s) {
            const int t = base_t + s;
            const float ts = fmaf(dt, (float)t + us[s], tnear);
            float dl;
            if (t == NS - 1) dl = (tfar + 1.0f) - ts;          // BOOSTER = 1.0
            else             dl = dt * (1.0f + us[s + 1] - us[s]);
            delta[s] = dl * dnorm;
            const float px = fmaf(dx, ts, ox);
            const float py = fmaf(dy, ts, oy);
            const float pz = fmaf(dz, ts, oz);
            const float nx = (px - lox) * sx - 1.0f;
            const float ny = (py - loy) * sy - 1.0f;
            const float nz = (pz - loz) * sz - 1.0f;
            nx2[s] = (f32x2){nx, nx};
            ny2[s] = (f32x2){ny, ny};
            nz2[s] = (f32x2){nz, nz};
        }

        // ---- MLP: weights read once, applied to 8 samples ----
        f32x2 cr2[SPL], cg2[SPL], cb2[SPL], dd2[SPL];
        #pragma unroll
        for (int s = 0; s < SPL; ++s) {
            cr2[s] = (f32x2){bc0, 0.0f};
            cg2[s] = (f32x2){bc1, 0.0f};
            cb2[s] = (f32x2){bc2, 0.0f};
            dd2[s] = (f32x2){bd0, 0.0f};
        }
        const float4* __restrict__ wq = reinterpret_cast<const float4*>(wsh);
        #pragma unroll 4
        for (int p = 0; p < HID / 2; ++p) {
            const float4 q0 = wq[p * 4 + 0];
            const float4 q1 = wq[p * 4 + 1];
            const float4 q2 = wq[p * 4 + 2];
            const float4 q3 = wq[p * 4 + 3];
            const f32x2 w1x = {q0.x, q0.y}, w1y = {q0.z, q0.w};
            const f32x2 w1z = {q1.x, q1.y}, b12 = {q1.z, q1.w};
            const f32x2 wcr = {q2.x, q2.y}, wcg = {q2.z, q2.w};
            const f32x2 wcb = {q3.x, q3.y}, wd2 = {q3.z, q3.w};
            #pragma unroll
            for (int s = 0; s < SPL; ++s) {
                f32x2 h2 = __builtin_elementwise_fma(nx2[s], w1x,
                           __builtin_elementwise_fma(ny2[s], w1y,
                           __builtin_elementwise_fma(nz2[s], w1z, b12)));
                h2 = __builtin_elementwise_max(h2, (f32x2){0.0f, 0.0f});
                cr2[s] = __builtin_elementwise_fma(h2, wcr, cr2[s]);
                cg2[s] = __builtin_elementwise_fma(h2, wcg, cg2[s]);
                cb2[s] = __builtin_elementwise_fma(h2, wcb, cb2[s]);
                dd2[s] = __builtin_elementwise_fma(h2, wd2, dd2[s]);
            }
        }

        // ---- density, local cumsum ----
        float sd[SPL], csum[SPL];
        float cum = 0.0f;
        #pragma unroll
        for (int s = 0; s < SPL; ++s) {
            const float dd = dd2[s].x + dd2[s].y;
            float dens = fmaxf(dd, 0.0f) + __logf(1.0f + __expf(-fabsf(dd)));
            const bool inbox = (fabsf(nx2[s].x) <= 1.0f) &&
                               (fabsf(ny2[s].x) <= 1.0f) &&
                               (fabsf(nz2[s].x) <= 1.0f);
            dens = inbox ? dens : 0.0f;   // w=0 then kills color+alpha, as ref
            sd[s] = dens * delta[s];
            cum += sd[s];
            csum[s] = cum;                // lane-local inclusive cumsum
        }

        // ---- single Kogge-Stone scan over lane totals ----
        float L = cum;
        #pragma unroll
        for (int off = 1; off < 64; off <<= 1) {
            const float v = __shfl_up(L, off);
            L += (lane >= off) ? v : 0.0f;
        }
        const float E = L - cum;          // exclusive prefix of this lane

        // ---- weights, colors, accumulate ----
        float accR = 0.0f, accG = 0.0f, accB = 0.0f, accA = 0.0f;
        #pragma unroll
        for (int s = 0; s < SPL; ++s) {
            const float Ci = E + csum[s];
            const float Ce = Ci - sd[s];
            const float w = __expf(-Ce) - __expf(-Ci);   // trans*(1-exp(-sd))
            const float cr = cr2[s].x + cr2[s].y;
            const float cg = cg2[s].x + cg2[s].y;
            const float cb = cb2[s].x + cb2[s].y;
            const float colR = __builtin_amdgcn_rcpf(1.0f + __expf(-cr));
            const float colG = __builtin_amdgcn_rcpf(1.0f + __expf(-cg));
            const float colB = __builtin_amdgcn_rcpf(1.0f + __expf(-cb));
            accR = fmaf(w, colR, accR);
            accG = fmaf(w, colG, accG);
            accB = fmaf(w, colB, accB);
            accA += w;
        }

        // ---- 64-lane butterfly sum ----
        #pragma unroll
        for (int off = 32; off; off >>= 1) {
            accR += __shfl_xor(accR, off);
            accG += __shfl_xor(accG, off);
            accB += __shfl_xor(accB, off);
            accA += __shfl_xor(accA, off);
        }
        res = make_float4(accR, accG, accB, accA);
    }

    if (lane == 0) {
        reinterpret_cast<float4*>(out)[ray] = res;
    }
}

extern "C" void kernel_launch(void* const* d_in, const int* in_sizes, int n_in,
                              void* d_out, int out_size, void* d_ws, size_t ws_size,
                              hipStream_t stream) {
    const float* o_   = (const float*)d_in[0];
    const float* d_   = (const float*)d_in[1];
    const float* aabb = (const float*)d_in[2];
    const float* u_   = (const float*)d_in[3];
    const float* W1   = (const float*)d_in[4];
    const float* b1   = (const float*)d_in[5];
    const float* Wc   = (const float*)d_in[6];
    const float* bc   = (const float*)d_in[7];
    const float* Wd   = (const float*)d_in[8];
    const float* bd   = (const float*)d_in[9];
    float* out = (float*)d_out;

    render_kernel<<<NRAYS / 4, 256, 0, stream>>>(o_, d_, aabb, u_, W1, b1, Wc, bc, Wd, bd, out);
}

// Round 8
// 108.594 us; speedup vs baseline: 1.6288x; 1.0668x over previous
//
#include <hip/hip_runtime.h>
#include <math.h>

#define NRAYS 8192
#define NS 512
#define HID 32
#define SPL 8   // samples per lane; 64 lanes * 8 = 512 = NS (one pass per ray)

typedef float f32x2 __attribute__((ext_vector_type(2)));

// One wave (64 lanes) per ray; lane i owns samples t = 8i..8i+7.
// Layer-1 is linear in ts: h_pre_j = A_j + B_j*ts with per-ray A,B recomputed
// per hidden-pair from LDS (6 pk ops, amortized over 8 samples). No per-sample
// xyz/ndc needed; in-box test dropped (samples in [tnear,tfar) are inside the
// box by construction; boundary-epsilon disagreements bounded << tolerance).
// Weight LDS layout per pair p (16 floats = 4 x b128):
//   [0..1]=W1[0][2p,2p+1] [2..3]=W1[1][..] [4..5]=W1[2][..] [6..7]=b1[..]
//   [8..9]=Wc[..][0] [10..11]=Wc[..][1] [12..13]=Wc[..][2] [14..15]=Wd[..]
// extras at [256..259] = {bc0,bc1,bc2,bd0}.
__global__ __launch_bounds__(256) void render_kernel(
    const float* __restrict__ o_, const float* __restrict__ d_,
    const float* __restrict__ aabb, const float* __restrict__ u_,
    const float* __restrict__ W1, const float* __restrict__ b1,
    const float* __restrict__ Wc, const float* __restrict__ bc,
    const float* __restrict__ Wd, const float* __restrict__ bd,
    float* __restrict__ out)
{
    __shared__ float wsh[272];
    const int tid = threadIdx.x;

    if (tid < HID) {
        const int j = tid, p = j >> 1, h = j & 1;
        float* base = wsh + p * 16;
        base[0 + h]  = W1[0 * HID + j];
        base[2 + h]  = W1[1 * HID + j];
        base[4 + h]  = W1[2 * HID + j];
        base[6 + h]  = b1[j];
        base[8 + h]  = Wc[j * 3 + 0];
        base[10 + h] = Wc[j * 3 + 1];
        base[12 + h] = Wc[j * 3 + 2];
        base[14 + h] = Wd[j];
    } else if (tid == HID) {
        wsh[256] = bc[0]; wsh[257] = bc[1]; wsh[258] = bc[2]; wsh[259] = bd[0];
    }
    __syncthreads();

    const int lane = tid & 63;
    const int ray  = (blockIdx.x << 2) + (tid >> 6);
    if (ray >= NRAYS) return;

    const float ox = o_[ray * 3 + 0], oy = o_[ray * 3 + 1], oz = o_[ray * 3 + 2];
    const float dx = d_[ray * 3 + 0], dy = d_[ray * 3 + 1], dz = d_[ray * 3 + 2];
    const float lox = aabb[0], loy = aabb[1], loz = aabb[2];
    const float hix = aabb[3], hiy = aabb[4], hiz = aabb[5];

    // Slab test (plain IEEE division; +-inf handled like the reference).
    float t1 = (lox - ox) / dx, t2 = (hix - ox) / dx;
    float tnear = fminf(t1, t2), tfar = fmaxf(t1, t2);
    t1 = (loy - oy) / dy; t2 = (hiy - oy) / dy;
    tnear = fmaxf(tnear, fminf(t1, t2)); tfar = fminf(tfar, fmaxf(t1, t2));
    t1 = (loz - oz) / dz; t2 = (hiz - oz) / dz;
    tnear = fmaxf(tnear, fminf(t1, t2)); tfar = fminf(tfar, fmaxf(t1, t2));
    tnear = fmaxf(tnear, 0.0f);

    float4 res = make_float4(0.0f, 0.0f, 0.0f, 0.0f);

    if (tnear < tfar) {  // active ray (wave-uniform branch)
        const float dnorm = sqrtf(dx * dx + dy * dy + dz * dz);
        const float dt = (tfar - tnear) * (1.0f / (float)NS);
        const float sx = 2.0f / (hix - lox);
        const float sy = 2.0f / (hiy - loy);
        const float sz = 2.0f / (hiz - loz);
        const float bc0 = wsh[256], bc1 = wsh[257], bc2 = wsh[258], bd0 = wsh[259];

        // ndc(ts) = c + g*ts, per axis (per-ray constants)
        const float cx = (ox - lox) * sx - 1.0f, gx = dx * sx;
        const float cy = (oy - loy) * sy - 1.0f, gy = dy * sy;
        const float cz = (oz - loz) * sz - 1.0f, gz = dz * sz;
        const f32x2 cx2 = {cx, cx}, cy2 = {cy, cy}, cz2 = {cz, cz};
        const f32x2 gx2 = {gx, gx}, gy2 = {gy, gy}, gz2 = {gz, gz};

        // ---- prologue: jitter, ts, deltas for this lane's 8 samples ----
        const int base_t = lane * SPL;
        const float* __restrict__ urow = u_ + (size_t)ray * NS + base_t;
        const float4 uaq = *reinterpret_cast<const float4*>(urow);
        const float4 ubq = *reinterpret_cast<const float4*>(urow + 4);
        float us[9];
        us[0] = uaq.x; us[1] = uaq.y; us[2] = uaq.z; us[3] = uaq.w;
        us[4] = ubq.x; us[5] = ubq.y; us[6] = ubq.z; us[7] = ubq.w;
        us[8] = __shfl_down(uaq.x, 1);   // u[8(i+1)]; lane 63 unused (tfar branch)

        float tsv[SPL], delta[SPL];
        #pragma unroll
        for (int s = 0; s < SPL; ++s) {
            const int t = base_t + s;
            tsv[s] = fmaf(dt, (float)t + us[s], tnear);
            float dl;
            if (t == NS - 1) dl = (tfar + 1.0f) - tsv[s];       // BOOSTER = 1.0
            else             dl = dt * (1.0f + us[s + 1] - us[s]);
            delta[s] = dl * dnorm;
        }

        // ---- MLP: layer-1 collapsed to h = relu(A + B*ts) ----
        f32x2 cr2[SPL], cg2[SPL], cb2[SPL], dd2[SPL];
        #pragma unroll
        for (int s = 0; s < SPL; ++s) {
            cr2[s] = (f32x2){bc0, 0.0f};
            cg2[s] = (f32x2){bc1, 0.0f};
            cb2[s] = (f32x2){bc2, 0.0f};
            dd2[s] = (f32x2){bd0, 0.0f};
        }
        const float4* __restrict__ wq = reinterpret_cast<const float4*>(wsh);
        #pragma unroll 4
        for (int p = 0; p < HID / 2; ++p) {
            const float4 q0 = wq[p * 4 + 0];
            const float4 q1 = wq[p * 4 + 1];
            const float4 q2 = wq[p * 4 + 2];
            const float4 q3 = wq[p * 4 + 3];
            const f32x2 w1x = {q0.x, q0.y}, w1y = {q0.z, q0.w};
            const f32x2 w1z = {q1.x, q1.y}, b12 = {q1.z, q1.w};
            const f32x2 wcr = {q2.x, q2.y}, wcg = {q2.z, q2.w};
            const f32x2 wcb = {q3.x, q3.y}, wd2 = {q3.z, q3.w};
            // A,B for this hidden pair (per-ray, amortized over 8 samples)
            const f32x2 A2 = __builtin_elementwise_fma(cx2, w1x,
                             __builtin_elementwise_fma(cy2, w1y,
                             __builtin_elementwise_fma(cz2, w1z, b12)));
            const f32x2 B2 = __builtin_elementwise_fma(gx2, w1x,
                             __builtin_elementwise_fma(gy2, w1y, gz2 * w1z));
            #pragma unroll
            for (int s = 0; s < SPL; ++s) {
                const f32x2 ts2 = {tsv[s], tsv[s]};
                f32x2 h2 = __builtin_elementwise_fma(ts2, B2, A2);
                h2 = __builtin_elementwise_max(h2, (f32x2){0.0f, 0.0f});
                cr2[s] = __builtin_elementwise_fma(h2, wcr, cr2[s]);
                cg2[s] = __builtin_elementwise_fma(h2, wcg, cg2[s]);
                cb2[s] = __builtin_elementwise_fma(h2, wcb, cb2[s]);
                dd2[s] = __builtin_elementwise_fma(h2, wd2, dd2[s]);
            }
        }

        // ---- density, local cumsum (no inbox mask: samples always in box) ----
        float sd[SPL], csum[SPL];
        float cum = 0.0f;
        #pragma unroll
        for (int s = 0; s < SPL; ++s) {
            const float dd = dd2[s].x + dd2[s].y;
            const float dens = fmaxf(dd, 0.0f) + __logf(1.0f + __expf(-fabsf(dd)));
            sd[s] = dens * delta[s];
            cum += sd[s];
            csum[s] = cum;
        }

        // ---- single Kogge-Stone scan over lane totals ----
        float L = cum;
        #pragma unroll
        for (int off = 1; off < 64; off <<= 1) {
            const float v = __shfl_up(L, off);
            L += (lane >= off) ? v : 0.0f;
        }
        const float E = L - cum;          // exclusive prefix of this lane

        // ---- weights (1 exp/sample via telescoping), colors, accumulate ----
        float accR = 0.0f, accG = 0.0f, accB = 0.0f;
        const float e0 = __expf(-E);
        float eprev = e0;
        #pragma unroll
        for (int s = 0; s < SPL; ++s) {
            const float ecur = __expf(-(E + csum[s]));
            const float w = eprev - ecur;   // exp(-Ce) - exp(-Ci)
            eprev = ecur;
            const float cr = cr2[s].x + cr2[s].y;
            const float cg = cg2[s].x + cg2[s].y;
            const float cb = cb2[s].x + cb2[s].y;
            const float colR = __builtin_amdgcn_rcpf(1.0f + __expf(-cr));
            const float colG = __builtin_amdgcn_rcpf(1.0f + __expf(-cg));
            const float colB = __builtin_amdgcn_rcpf(1.0f + __expf(-cb));
            accR = fmaf(w, colR, accR);
            accG = fmaf(w, colG, accG);
            accB = fmaf(w, colB, accB);
        }
        float accA = e0 - eprev;            // telescoped per-lane alpha

        // ---- 64-lane butterfly sum ----
        #pragma unroll
        for (int off = 32; off; off >>= 1) {
            accR += __shfl_xor(accR, off);
            accG += __shfl_xor(accG, off);
            accB += __shfl_xor(accB, off);
            accA += __shfl_xor(accA, off);
        }
        res = make_float4(accR, accG, accB, accA);
    }

    if (lane == 0) {
        reinterpret_cast<float4*>(out)[ray] = res;
    }
}

extern "C" void kernel_launch(void* const* d_in, const int* in_sizes, int n_in,
                              void* d_out, int out_size, void* d_ws, size_t ws_size,
                              hipStream_t stream) {
    const float* o_   = (const float*)d_in[0];
    const float* d_   = (const float*)d_in[1];
    const float* aabb = (const float*)d_in[2];
    const float* u_   = (const float*)d_in[3];
    const float* W1   = (const float*)d_in[4];
    const float* b1   = (const float*)d_in[5];
    const float* Wc   = (const float*)d_in[6];
    const float* bc   = (const float*)d_in[7];
    const float* Wd   = (const float*)d_in[8];
    const float* bd   = (const float*)d_in[9];
    float* out = (float*)d_out;

    render_kernel<<<NRAYS / 4, 256, 0, stream>>>(o_, d_, aabb, u_, W1, b1, Wc, bc, Wd, bd, out);
}